// Round 4
// baseline (902.639 us; speedup 1.0000x reference)
//
#include <hip/hip_runtime.h>
#include <math.h>

#define H 224
#define W 224
#define C 196
#define NB 10
#define NUM_ITERS 50
#define B 64
#define HW (H*W)
#define TS 56
#define KCAND 8
#define COLOR_WEIGHT 10.0f
#define GRAD_WEIGHT 10.0f

// ---------------- fused grad map + wgm + V/H color diffs ----------------
__global__ __launch_bounds__(256) void gradcw_kernel(const float* __restrict__ x,
                              const float* __restrict__ wgt,
                              float* __restrict__ wgm, float* __restrict__ out_grad,
                              float* __restrict__ cwV, float* __restrict__ cwH) {
    __shared__ float gray[10][34];   // (8+2) x (32+2) halo tile
    int blk = blockIdx.x;
    int b = blk / 196;
    int t = blk - b * 196;
    int by = (t / 7) * 8;            // 28 tile-rows
    int bx = (t - (t / 7) * 7) * 32; // 7 tile-cols
    const float* xb = x + (size_t)b * 3 * HW;
    int tid = threadIdx.x;
    for (int e = tid; e < 340; e += 256) {
        int ly = e / 34, lx = e - (e / 34) * 34;
        int gy = by - 1 + ly, gx = bx - 1 + lx;
        float g = 0.f;
        if (gy >= 0 && gy < H && gx >= 0 && gx < W) {
            int q = gy * W + gx;
            g = __fadd_rn(__fadd_rn(__fmul_rn(0.2989f, xb[q]), __fmul_rn(0.587f, xb[HW + q])),
                          __fmul_rn(0.114f, xb[2 * HW + q]));
        }
        gray[ly][lx] = g;
    }
    __syncthreads();
    int ty2 = tid >> 5, tx2 = tid & 31;
    int h = by + ty2, w = bx + tx2;
    int p = h * W + w;
    int idx = b * HW + p;
    float ax = 0.f, ay = 0.f;
    #pragma unroll
    for (int ky = 0; ky < 3; ky++) {
        #pragma unroll
        for (int kx = 0; kx < 3; kx++) {
            float g = gray[ty2 + ky][tx2 + kx];
            ax = __fadd_rn(ax, __fmul_rn(wgt[ky * 3 + kx], g));
            ay = __fadd_rn(ay, __fmul_rn(wgt[9 + ky * 3 + kx], g));
        }
    }
    float s = __fadd_rn(__fadd_rn(__fmul_rn(ax, ax), __fmul_rn(ay, ay)), 1e-8f);
    float gv = sqrtf(s);
    out_grad[idx] = gv;
    wgm[idx] = __fmul_rn(powf(gv, 4.0f), GRAD_WEIGHT);  // powf kept: bit-identical

    float r0 = xb[p];
    float g0 = xb[HW + p];
    float b0 = xb[2 * HW + p];
    int hd_ = (h + 1 >= H) ? 0 : h + 1;
    int wd_ = (w + 1 >= W) ? 0 : w + 1;
    int qd = hd_ * W + w;
    int qr = h * W + wd_;
    float dv = __fadd_rn(__fadd_rn(fabsf(__fsub_rn(r0, xb[qd])), fabsf(__fsub_rn(g0, xb[HW + qd]))),
                         fabsf(__fsub_rn(b0, xb[2 * HW + qd])));
    float dh = __fadd_rn(__fadd_rn(fabsf(__fsub_rn(r0, xb[qr])), fabsf(__fsub_rn(g0, xb[HW + qr]))),
                         fabsf(__fsub_rn(b0, xb[2 * HW + qr])));
    cwV[idx] = __fmul_rn(dv, COLOR_WEIGHT);
    cwH[idx] = __fmul_rn(dh, COLOR_WEIGHT);
}

// ---------------- parallel per-centroid window argmin (candidates) ----------------
__global__ void cand_kernel(const float* __restrict__ grad, int* __restrict__ cand,
                            int* __restrict__ cnt) {
    int gtid = blockIdx.x * blockDim.x + threadIdx.x;
    int wid = gtid >> 6;
    int lane = threadIdx.x & 63;
    if (wid >= B * C) return;
    int b = wid / C, c = wid - b * C;
    const float* gb = grad + (size_t)b * HW;
    int cy = 8 + 16 * (c / 14), cx = 8 + 16 * (c % 14);
    int ymin = max(0, cy - NB), ymax = min(H, cy + NB);
    int xmin = max(0, cx - NB), xmax = min(W, cx + NB);
    int rh = ymax - ymin, rw = xmax - xmin;
    float v[7];
    float lmin = INFINITY;
    #pragma unroll
    for (int i = 0; i < 7; i++) {
        int cell = lane + 64 * i;
        float val = INFINITY;
        if (cell < 400) {
            int r = cell / 20, cc = cell - (cell / 20) * 20;
            if (r < rh && cc < rw) val = gb[(ymin + r) * W + xmin + cc];
        }
        v[i] = val;
        lmin = fminf(lmin, val);
    }
    #pragma unroll
    for (int m = 1; m < 64; m <<= 1) lmin = fminf(lmin, __shfl_xor(lmin, m, 64));
    float mv = lmin;
    int n = 0;
    int base = wid * KCAND;
    #pragma unroll
    for (int i = 0; i < 7; i++) {
        unsigned long long msk = __ballot(v[i] == mv);
        if (lane == 0) {
            while (msk) {
                int bit = __ffsll(msk) - 1;
                msk &= msk - 1;
                int cell = bit + 64 * i;
                if (n < KCAND) {
                    int r = cell / 20, cc = cell - (cell / 20) * 20;
                    cand[base + n] = (ymin + r) * W + (xmin + cc);
                }
                n++;
            }
        }
    }
    if (lane == 0) cnt[wid] = n;
}

// ---------------- wavefront-parallel occupancy resolve ----------------
__global__ void resolve_kernel(const float* __restrict__ grad,
                               const int* __restrict__ cand, const int* __restrict__ cnt,
                               int* __restrict__ cents_i, float* __restrict__ out_cents) {
    __shared__ unsigned char occ[HW];
    __shared__ int scand[C * KCAND];
    __shared__ int scnt[C];
    int b = blockIdx.x;
    int t = threadIdx.x;
    for (int i = t; i < HW / 4; i += 256) ((int*)occ)[i] = 0;
    for (int i = t; i < C * KCAND; i += 256) scand[i] = cand[b * C * KCAND + i];
    for (int i = t; i < C; i += 256) scnt[i] = cnt[b * C + i];
    __syncthreads();
    int c = t;
    int gi = c / 14, gj = c - 14 * (c / 14);
    int myround = 2 * gi + gj;
    for (int r = 0; r < 40; r++) {
        if (c < C && myround == r) {
            int n = scnt[c];
            int ny = 0, nx = 0;
            bool found = false;
            if (n <= KCAND) {
                for (int k = 0; k < n; k++) {
                    int pos = scand[c * KCAND + k];
                    if (!occ[pos]) {
                        found = true; ny = pos / W; nx = pos - (pos / W) * W;
                        occ[pos] = 1; break;
                    }
                }
            } else {
                const float* gb = grad + (size_t)b * HW;
                int cy = 8 + 16 * gi, cx = 8 + 16 * gj;
                int ymin = max(0, cy - NB), ymax = min(H, cy + NB);
                int xmin = max(0, cx - NB), xmax = min(W, cx + NB);
                float mv = INFINITY;
                for (int rr = ymin; rr < ymax; rr++)
                    for (int cc = xmin; cc < xmax; cc++)
                        mv = fminf(mv, gb[rr * W + cc]);
                for (int rr = ymin; rr < ymax && !found; rr++)
                    for (int cc = xmin; cc < xmax && !found; cc++)
                        if (gb[rr * W + cc] == mv && !occ[rr * W + cc]) {
                            found = true; ny = rr; nx = cc; occ[rr * W + cc] = 1;
                        }
            }
            if (!found) { ny = 8 + 16 * gi; nx = 8 + 16 * gj; }
            cents_i[(b * C + c) * 2 + 0] = ny;
            cents_i[(b * C + c) * 2 + 1] = nx;
            out_cents[(b * C + c) * 2 + 0] = (float)ny;
            out_cents[(b * C + c) * 2 + 1] = (float)nx;
        }
        __syncthreads();
    }
}

// ---------------- fused propagation: shfl transport, 2 barriers/iter ----------------
// Wave layout: 256 threads, tx=tid&15, ty=tid>>4 -> one wave = 4 full thread-rows.
// Horizontal passes (DIR2/3): neighbor tid+-1 always in-wave -> pure shfl, no barrier.
// Vertical passes (DIR0/1): neighbor tid+-16 in-wave except every 4th row -> shfl +
// a 16-thread-per-wave LDS exchange + 1 barrier.
__device__ __forceinline__ int wrapc(int v) {
    v += (v < 0) ? 224 : 0;
    v -= (v >= 224) ? 224 : 0;
    return v;
}
__device__ __forceinline__ uint2 packm(int a, int b_, int c_, int d_) {
    uint2 r;
    r.x = (a & 0xffff) | (b_ << 16);
    r.y = (c_ & 0xffff) | (d_ << 16);
    return r;
}

template<int DIR>
__device__ __forceinline__ void do_pass(float (&D)[4][4], int (&M)[4][4],
    const float (&Wg)[4][4], const float (&Vv)[5][4], const float (&Hh)[4][5],
    float4* __restrict__ bd, uint2* __restrict__ bm, int ty, int tx)
{
    float nb[4]; int nbm[4];
    if (DIR == 0 || DIR == 1) {
        const int r = (DIR == 0) ? 0 : 3;
        float4 pd = make_float4(D[r][0], D[r][1], D[r][2], D[r][3]);
        uint2 pm = packm(M[r][0], M[r][1], M[r][2], M[r][3]);
        bool pub = (DIR == 0) ? (((ty & 3) == 0) && ty > 0)
                              : (((ty & 3) == 3) && ty < 15);
        if (pub) {
            int ps = (DIR == 0) ? (((ty >> 2) - 1) * 16 + tx) : ((ty >> 2) * 16 + tx);
            bd[ps] = pd; bm[ps] = pm;
        }
        float n0, n1, n2, n3; unsigned px, py;
        if (DIR == 0) {
            n0 = __shfl_down(pd.x, 16, 64); n1 = __shfl_down(pd.y, 16, 64);
            n2 = __shfl_down(pd.z, 16, 64); n3 = __shfl_down(pd.w, 16, 64);
            px = __shfl_down(pm.x, 16, 64); py = __shfl_down(pm.y, 16, 64);
        } else {
            n0 = __shfl_up(pd.x, 16, 64); n1 = __shfl_up(pd.y, 16, 64);
            n2 = __shfl_up(pd.z, 16, 64); n3 = __shfl_up(pd.w, 16, 64);
            px = __shfl_up(pm.x, 16, 64); py = __shfl_up(pm.y, 16, 64);
        }
        __syncthreads();
        bool edge = (DIR == 0) ? ((ty & 3) == 3) : ((ty & 3) == 0);
        if (edge) {
            bool bound = (DIR == 0) ? (ty == 15) : (ty == 0);
            if (!bound) {
                int s = (DIR == 0) ? ((ty >> 2) * 16 + tx) : (((ty >> 2) - 1) * 16 + tx);
                float4 t = bd[s]; uint2 u = bm[s];
                n0 = t.x; n1 = t.y; n2 = t.z; n3 = t.w; px = u.x; py = u.y;
            } else { n0 = n1 = n2 = n3 = INFINITY; px = py = 0u; }
        }
        nb[0]=n0; nb[1]=n1; nb[2]=n2; nb[3]=n3;
        nbm[0]=(int)(short)(px & 0xffff); nbm[1]=(int)(short)(px >> 16);
        nbm[2]=(int)(short)(py & 0xffff); nbm[3]=(int)(short)(py >> 16);
    } else {
        const int c = (DIR == 2) ? 0 : 3;
        uint2 pm = packm(M[0][c], M[1][c], M[2][c], M[3][c]);
        float n0, n1, n2, n3; unsigned px, py;
        if (DIR == 2) {
            n0 = __shfl_down(D[0][c], 1, 64); n1 = __shfl_down(D[1][c], 1, 64);
            n2 = __shfl_down(D[2][c], 1, 64); n3 = __shfl_down(D[3][c], 1, 64);
            px = __shfl_down(pm.x, 1, 64); py = __shfl_down(pm.y, 1, 64);
        } else {
            n0 = __shfl_up(D[0][c], 1, 64); n1 = __shfl_up(D[1][c], 1, 64);
            n2 = __shfl_up(D[2][c], 1, 64); n3 = __shfl_up(D[3][c], 1, 64);
            px = __shfl_up(pm.x, 1, 64); py = __shfl_up(pm.y, 1, 64);
        }
        bool bound = (DIR == 2) ? (tx == 15) : (tx == 0);
        if (bound) { n0 = n1 = n2 = n3 = INFINITY; px = py = 0u; }
        nb[0]=n0; nb[1]=n1; nb[2]=n2; nb[3]=n3;
        nbm[0]=(int)(short)(px & 0xffff); nbm[1]=(int)(short)(px >> 16);
        nbm[2]=(int)(short)(py & 0xffff); nbm[3]=(int)(short)(py >> 16);
    }
    // identical arithmetic / update order to the verified kernel
    if (DIR == 0) {
        #pragma unroll
        for (int i = 0; i < 4; i++)
            #pragma unroll
            for (int j = 0; j < 4; j++) {
                float sd = (i < 3) ? D[i+1][j] : nb[j];
                int   sm = (i < 3) ? M[i+1][j] : nbm[j];
                float wd = __fadd_rn(__fadd_rn(sd, Wg[i][j]), Vv[i+1][j]);
                if (wd < D[i][j]) { D[i][j] = wd; M[i][j] = sm; }
            }
    } else if (DIR == 1) {
        #pragma unroll
        for (int i = 3; i >= 0; i--)
            #pragma unroll
            for (int j = 0; j < 4; j++) {
                float sd = (i > 0) ? D[i-1][j] : nb[j];
                int   sm = (i > 0) ? M[i-1][j] : nbm[j];
                float wd = __fadd_rn(__fadd_rn(sd, Wg[i][j]), Vv[i][j]);
                if (wd < D[i][j]) { D[i][j] = wd; M[i][j] = sm; }
            }
    } else if (DIR == 2) {
        #pragma unroll
        for (int i = 0; i < 4; i++)
            #pragma unroll
            for (int j = 0; j < 4; j++) {
                float sd = (j < 3) ? D[i][j+1] : nb[i];
                int   sm = (j < 3) ? M[i][j+1] : nbm[i];
                float wd = __fadd_rn(__fadd_rn(sd, Wg[i][j]), Hh[i][j+1]);
                if (wd < D[i][j]) { D[i][j] = wd; M[i][j] = sm; }
            }
    } else {
        #pragma unroll
        for (int i = 0; i < 4; i++)
            #pragma unroll
            for (int j = 3; j >= 0; j--) {
                float sd = (j > 0) ? D[i][j-1] : nb[i];
                int   sm = (j > 0) ? M[i][j-1] : nbm[i];
                float wd = __fadd_rn(__fadd_rn(sd, Wg[i][j]), Hh[i][j]);
                if (wd < D[i][j]) { D[i][j] = wd; M[i][j] = sm; }
            }
    }
}

// seed mode (cents != nullptr): LDS atomicMax seed tile (max-c == XLA scatter
// later-index-wins; verified in round-3 pass). No global dist/mask read.
__global__ __launch_bounds__(256, 4) void prop_fused(
    const float* __restrict__ din, const short* __restrict__ min_,
    float* __restrict__ dout, short* __restrict__ mout,
    const float* __restrict__ wgm, const float* __restrict__ cwV,
    const float* __restrict__ cwH, const int* __restrict__ cents,
    int n_it, float* __restrict__ out_mask)
{
    __shared__ float4 bd0[48]; __shared__ uint2 bm0[48];
    __shared__ float4 bd1[48]; __shared__ uint2 bm1[48];
    __shared__ int seedv[64 * 64];
    int blk = blockIdx.x;
    int b = blk >> 4, tile = blk & 15;
    int ty0 = (tile >> 2) * TS, tx0 = (tile & 3) * TS;
    int tid = threadIdx.x;
    int tx = tid & 15, ty = tid >> 4;
    int gx0 = wrapc(tx0 + 4 * tx - 4);
    int cm1 = wrapc(gx0 - 1);
    int rowoff[4];
    #pragma unroll
    for (int i = 0; i < 4; i++) {
        int y = wrapc(ty0 + 4 * ty - 4 + i);
        rowoff[i] = y * W + gx0;
    }
    int rowm1 = wrapc(ty0 + 4 * ty - 5) * W + gx0;
    const float* wgmb = wgm + (size_t)b * HW;
    const float* Vb = cwV + (size_t)b * HW;
    const float* Hb = cwH + (size_t)b * HW;
    float D[4][4]; int M[4][4]; float Wg[4][4]; float Vv[5][4]; float Hh[4][5];
    {
        float4 v0 = *(const float4*)(Vb + rowm1);
        Vv[0][0] = v0.x; Vv[0][1] = v0.y; Vv[0][2] = v0.z; Vv[0][3] = v0.w;
    }
    #pragma unroll
    for (int i = 0; i < 4; i++) {
        float4 wv = *(const float4*)(wgmb + rowoff[i]);
        float4 vv = *(const float4*)(Vb + rowoff[i]);
        float4 hh = *(const float4*)(Hb + rowoff[i]);
        Wg[i][0] = wv.x; Wg[i][1] = wv.y; Wg[i][2] = wv.z; Wg[i][3] = wv.w;
        Vv[i+1][0] = vv.x; Vv[i+1][1] = vv.y; Vv[i+1][2] = vv.z; Vv[i+1][3] = vv.w;
        Hh[i][1] = hh.x; Hh[i][2] = hh.y; Hh[i][3] = hh.z; Hh[i][4] = hh.w;
        Hh[i][0] = Hb[rowoff[i] - gx0 + cm1];
    }
    if (cents) {
        for (int e = tid; e < 64 * 64; e += 256) seedv[e] = -1;
        __syncthreads();
        if (tid < C) {
            int cy = cents[(b * C + tid) * 2 + 0];
            int cx = cents[(b * C + tid) * 2 + 1];
            int ly = cy - (ty0 - 4); ly += (ly < 0) ? 224 : 0; ly -= (ly >= 224) ? 224 : 0;
            int lx = cx - (tx0 - 4); lx += (lx < 0) ? 224 : 0; lx -= (lx >= 224) ? 224 : 0;
            if (ly < 64 && lx < 64) atomicMax(&seedv[ly * 64 + lx], tid);
        }
        __syncthreads();
        #pragma unroll
        for (int i = 0; i < 4; i++)
            #pragma unroll
            for (int j = 0; j < 4; j++) {
                int s = seedv[(4 * ty + i) * 64 + 4 * tx + j];
                D[i][j] = (s >= 0) ? 0.f : INFINITY;
                M[i][j] = s;
            }
    } else {
        const float* dinb = din + (size_t)b * HW;
        const short* minb = min_ + (size_t)b * HW;
        #pragma unroll
        for (int i = 0; i < 4; i++) {
            float4 dv = *(const float4*)(dinb + rowoff[i]);
            uint2  mv = *(const uint2*)(minb + rowoff[i]);
            D[i][0] = dv.x; D[i][1] = dv.y; D[i][2] = dv.z; D[i][3] = dv.w;
            M[i][0] = (int)(short)(mv.x & 0xffff); M[i][1] = (int)(short)(mv.x >> 16);
            M[i][2] = (int)(short)(mv.y & 0xffff); M[i][3] = (int)(short)(mv.y >> 16);
        }
    }
    #pragma unroll 1
    for (int it = 0; it < n_it; ++it) {
        do_pass<0>(D, M, Wg, Vv, Hh, bd0, bm0, ty, tx);
        do_pass<1>(D, M, Wg, Vv, Hh, bd1, bm1, ty, tx);
        do_pass<2>(D, M, Wg, Vv, Hh, bd0, bm0, ty, tx);
        do_pass<3>(D, M, Wg, Vv, Hh, bd1, bm1, ty, tx);
    }
    if (ty >= 1 && ty < 15 && tx >= 1 && tx < 15) {
        if (out_mask) {
            float* omb = out_mask + (size_t)b * HW;
            #pragma unroll
            for (int i = 0; i < 4; i++)
                *(float4*)(omb + rowoff[i]) =
                    make_float4((float)M[i][0], (float)M[i][1], (float)M[i][2], (float)M[i][3]);
        } else {
            float* doutb = dout + (size_t)b * HW;
            short* moutb = mout + (size_t)b * HW;
            #pragma unroll
            for (int i = 0; i < 4; i++) {
                *(float4*)(doutb + rowoff[i]) = make_float4(D[i][0], D[i][1], D[i][2], D[i][3]);
                *(uint2*)(moutb + rowoff[i]) = packm(M[i][0], M[i][1], M[i][2], M[i][3]);
            }
        }
    }
}

extern "C" void kernel_launch(void* const* d_in, const int* in_sizes, int n_in,
                              void* d_out, int out_size, void* d_ws, size_t ws_size,
                              hipStream_t stream) {
    const float* x   = (const float*)d_in[0];
    const float* wgt = (const float*)d_in[1];
    float* out = (float*)d_out;
    float* out_grad  = out;
    float* out_cents = out + (size_t)B * HW;
    float* out_mask  = out + (size_t)B * HW + (size_t)B * C * 2;

    char* ws = (char*)d_ws;
    const size_t n = (size_t)B * HW;
    float* wgm    = (float*)ws;                ws += sizeof(float) * n;
    float* cwV    = (float*)ws;                ws += sizeof(float) * n;
    float* cwH    = (float*)ws;                ws += sizeof(float) * n;
    float* dist_a = (float*)ws;                ws += sizeof(float) * n;
    float* dist_b = (float*)ws;                ws += sizeof(float) * n;
    short* mask_a = (short*)ws;                ws += sizeof(short) * n;
    short* mask_b = (short*)ws;                ws += sizeof(short) * n;
    int*   cents_i = (int*)ws;                 ws += sizeof(int) * B * C * 2;
    // cand/cnt alias dist_b: live only between cand_kernel and resolve_kernel,
    // both of which precede the first prop write of dist_b (stream-ordered).
    int* cand = (int*)dist_b;
    int* cnt  = cand + (size_t)B * C * KCAND;

    gradcw_kernel<<<B * 196, 256, 0, stream>>>(x, wgt, wgm, out_grad, cwV, cwH);
    cand_kernel<<<(B * C) / 4, 256, 0, stream>>>(out_grad, cand, cnt);
    resolve_kernel<<<B, 256, 0, stream>>>(out_grad, cand, cnt, cents_i, out_cents);

    // 13 launches: 12x4 + 1x2 = 50 iterations. Launch 1 seeds in-kernel
    // (init/seed kernels eliminated) and writes dist_b (cand/cnt already dead).
    float* da = dist_a; float* db = dist_b;
    short* ma = mask_a; short* mb = mask_b;
    int done = 0; bool first = true;
    while (done < NUM_ITERS) {
        int n_it = (NUM_ITERS - done) < 4 ? (NUM_ITERS - done) : 4;
        bool last = (done + n_it) == NUM_ITERS;
        prop_fused<<<B * 16, 256, 0, stream>>>(da, ma, db, mb, wgm, cwV, cwH,
                                               first ? cents_i : (const int*)nullptr,
                                               n_it, last ? out_mask : (float*)nullptr);
        float* td = da; da = db; db = td;
        short* tm = ma; ma = mb; mb = tm;
        done += n_it; first = false;
    }
}

// Round 5
// 480.483 us; speedup vs baseline: 1.8786x; 1.8786x over previous
//
#include <hip/hip_runtime.h>
#include <math.h>

#define H 224
#define W 224
#define C 196
#define NB 10
#define NUM_ITERS 50
#define B 64
#define HW (H*W)
#define TS 56
#define KCAND 8
#define COLOR_WEIGHT 10.0f
#define GRAD_WEIGHT 10.0f

// ---------------- fused grad map + wgm + V/H color diffs ----------------
__global__ __launch_bounds__(256) void gradcw_kernel(const float* __restrict__ x,
                              const float* __restrict__ wgt,
                              float* __restrict__ wgm, float* __restrict__ out_grad,
                              float* __restrict__ cwV, float* __restrict__ cwH) {
    __shared__ float gray[10][34];   // (8+2) x (32+2) halo tile
    int blk = blockIdx.x;
    int b = blk / 196;
    int t = blk - b * 196;
    int by = (t / 7) * 8;            // 28 tile-rows
    int bx = (t - (t / 7) * 7) * 32; // 7 tile-cols
    const float* xb = x + (size_t)b * 3 * HW;
    int tid = threadIdx.x;
    for (int e = tid; e < 340; e += 256) {
        int ly = e / 34, lx = e - (e / 34) * 34;
        int gy = by - 1 + ly, gx = bx - 1 + lx;
        float g = 0.f;
        if (gy >= 0 && gy < H && gx >= 0 && gx < W) {
            int q = gy * W + gx;
            g = __fadd_rn(__fadd_rn(__fmul_rn(0.2989f, xb[q]), __fmul_rn(0.587f, xb[HW + q])),
                          __fmul_rn(0.114f, xb[2 * HW + q]));
        }
        gray[ly][lx] = g;
    }
    __syncthreads();
    int ty2 = tid >> 5, tx2 = tid & 31;
    int h = by + ty2, w = bx + tx2;
    int p = h * W + w;
    int idx = b * HW + p;
    float ax = 0.f, ay = 0.f;
    #pragma unroll
    for (int ky = 0; ky < 3; ky++) {
        #pragma unroll
        for (int kx = 0; kx < 3; kx++) {
            float g = gray[ty2 + ky][tx2 + kx];
            ax = __fadd_rn(ax, __fmul_rn(wgt[ky * 3 + kx], g));
            ay = __fadd_rn(ay, __fmul_rn(wgt[9 + ky * 3 + kx], g));
        }
    }
    float s = __fadd_rn(__fadd_rn(__fmul_rn(ax, ax), __fmul_rn(ay, ay)), 1e-8f);
    float gv = sqrtf(s);
    out_grad[idx] = gv;
    wgm[idx] = __fmul_rn(powf(gv, 4.0f), GRAD_WEIGHT);  // powf kept: bit-identical

    float r0 = xb[p];
    float g0 = xb[HW + p];
    float b0 = xb[2 * HW + p];
    int hd_ = (h + 1 >= H) ? 0 : h + 1;
    int wd_ = (w + 1 >= W) ? 0 : w + 1;
    int qd = hd_ * W + w;
    int qr = h * W + wd_;
    float dv = __fadd_rn(__fadd_rn(fabsf(__fsub_rn(r0, xb[qd])), fabsf(__fsub_rn(g0, xb[HW + qd]))),
                         fabsf(__fsub_rn(b0, xb[2 * HW + qd])));
    float dh = __fadd_rn(__fadd_rn(fabsf(__fsub_rn(r0, xb[qr])), fabsf(__fsub_rn(g0, xb[HW + qr]))),
                         fabsf(__fsub_rn(b0, xb[2 * HW + qr])));
    cwV[idx] = __fmul_rn(dv, COLOR_WEIGHT);
    cwH[idx] = __fmul_rn(dh, COLOR_WEIGHT);
}

// ---------------- parallel per-centroid window argmin (candidates) ----------------
__global__ void cand_kernel(const float* __restrict__ grad, int* __restrict__ cand,
                            int* __restrict__ cnt) {
    int gtid = blockIdx.x * blockDim.x + threadIdx.x;
    int wid = gtid >> 6;
    int lane = threadIdx.x & 63;
    if (wid >= B * C) return;
    int b = wid / C, c = wid - b * C;
    const float* gb = grad + (size_t)b * HW;
    int cy = 8 + 16 * (c / 14), cx = 8 + 16 * (c % 14);
    int ymin = max(0, cy - NB), ymax = min(H, cy + NB);
    int xmin = max(0, cx - NB), xmax = min(W, cx + NB);
    int rh = ymax - ymin, rw = xmax - xmin;
    float v[7];
    float lmin = INFINITY;
    #pragma unroll
    for (int i = 0; i < 7; i++) {
        int cell = lane + 64 * i;
        float val = INFINITY;
        if (cell < 400) {
            int r = cell / 20, cc = cell - (cell / 20) * 20;
            if (r < rh && cc < rw) val = gb[(ymin + r) * W + xmin + cc];
        }
        v[i] = val;
        lmin = fminf(lmin, val);
    }
    #pragma unroll
    for (int m = 1; m < 64; m <<= 1) lmin = fminf(lmin, __shfl_xor(lmin, m, 64));
    float mv = lmin;
    int n = 0;
    int base = wid * KCAND;
    #pragma unroll
    for (int i = 0; i < 7; i++) {
        unsigned long long msk = __ballot(v[i] == mv);
        if (lane == 0) {
            while (msk) {
                int bit = __ffsll(msk) - 1;
                msk &= msk - 1;
                int cell = bit + 64 * i;
                if (n < KCAND) {
                    int r = cell / 20, cc = cell - (cell / 20) * 20;
                    cand[base + n] = (ymin + r) * W + (xmin + cc);
                }
                n++;
            }
        }
    }
    if (lane == 0) cnt[wid] = n;
}

// ---------------- wavefront-parallel occupancy resolve ----------------
__global__ void resolve_kernel(const float* __restrict__ grad,
                               const int* __restrict__ cand, const int* __restrict__ cnt,
                               int* __restrict__ cents_i, float* __restrict__ out_cents) {
    __shared__ unsigned char occ[HW];
    __shared__ int scand[C * KCAND];
    __shared__ int scnt[C];
    int b = blockIdx.x;
    int t = threadIdx.x;
    for (int i = t; i < HW / 4; i += 256) ((int*)occ)[i] = 0;
    for (int i = t; i < C * KCAND; i += 256) scand[i] = cand[b * C * KCAND + i];
    for (int i = t; i < C; i += 256) scnt[i] = cnt[b * C + i];
    __syncthreads();
    int c = t;
    int gi = c / 14, gj = c - 14 * (c / 14);
    int myround = 2 * gi + gj;
    for (int r = 0; r < 40; r++) {
        if (c < C && myround == r) {
            int n = scnt[c];
            int ny = 0, nx = 0;
            bool found = false;
            if (n <= KCAND) {
                for (int k = 0; k < n; k++) {
                    int pos = scand[c * KCAND + k];
                    if (!occ[pos]) {
                        found = true; ny = pos / W; nx = pos - (pos / W) * W;
                        occ[pos] = 1; break;
                    }
                }
            } else {
                const float* gb = grad + (size_t)b * HW;
                int cy = 8 + 16 * gi, cx = 8 + 16 * gj;
                int ymin = max(0, cy - NB), ymax = min(H, cy + NB);
                int xmin = max(0, cx - NB), xmax = min(W, cx + NB);
                float mv = INFINITY;
                for (int rr = ymin; rr < ymax; rr++)
                    for (int cc = xmin; cc < xmax; cc++)
                        mv = fminf(mv, gb[rr * W + cc]);
                for (int rr = ymin; rr < ymax && !found; rr++)
                    for (int cc = xmin; cc < xmax && !found; cc++)
                        if (gb[rr * W + cc] == mv && !occ[rr * W + cc]) {
                            found = true; ny = rr; nx = cc; occ[rr * W + cc] = 1;
                        }
            }
            if (!found) { ny = 8 + 16 * gi; nx = 8 + 16 * gj; }
            cents_i[(b * C + c) * 2 + 0] = ny;
            cents_i[(b * C + c) * 2 + 1] = nx;
            out_cents[(b * C + c) * 2 + 0] = (float)ny;
            out_cents[(b * C + c) * 2 + 1] = (float)nx;
        }
        __syncthreads();
    }
}

// ---------------- fused propagation: shfl transport, 2 barriers/iter ----------------
// Wave layout: 256 threads, tx=tid&15, ty=tid>>4 -> one wave = 4 full thread-rows.
// Horizontal passes (DIR2/3): neighbor tid+-1 always in-wave -> pure shfl, no barrier.
// Vertical passes (DIR0/1): neighbor tid+-16 in-wave except every 4th row -> shfl +
// a 16-thread-per-wave LDS exchange + 1 barrier.
// NOTE: plain __launch_bounds__(256) -- NO min-waves arg. (256,4) capped VGPRs at
// 64 and spilled the ~100-reg tile state to scratch (r4: +90MB/dispatch scratch
// traffic, VALUBusy 15%). Uncapped: state fits, ~3 blocks/CU, zero scratch.
__device__ __forceinline__ int wrapc(int v) {
    v += (v < 0) ? 224 : 0;
    v -= (v >= 224) ? 224 : 0;
    return v;
}
__device__ __forceinline__ uint2 packm(int a, int b_, int c_, int d_) {
    uint2 r;
    r.x = (a & 0xffff) | (b_ << 16);
    r.y = (c_ & 0xffff) | (d_ << 16);
    return r;
}

template<int DIR>
__device__ __forceinline__ void do_pass(float (&D)[4][4], int (&M)[4][4],
    const float (&Wg)[4][4], const float (&Vv)[5][4], const float (&Hh)[4][5],
    float4* __restrict__ bd, uint2* __restrict__ bm, int ty, int tx)
{
    float nb[4]; int nbm[4];
    if (DIR == 0 || DIR == 1) {
        const int r = (DIR == 0) ? 0 : 3;
        float4 pd = make_float4(D[r][0], D[r][1], D[r][2], D[r][3]);
        uint2 pm = packm(M[r][0], M[r][1], M[r][2], M[r][3]);
        bool pub = (DIR == 0) ? (((ty & 3) == 0) && ty > 0)
                              : (((ty & 3) == 3) && ty < 15);
        if (pub) {
            int ps = (DIR == 0) ? (((ty >> 2) - 1) * 16 + tx) : ((ty >> 2) * 16 + tx);
            bd[ps] = pd; bm[ps] = pm;
        }
        float n0, n1, n2, n3; unsigned px, py;
        if (DIR == 0) {
            n0 = __shfl_down(pd.x, 16, 64); n1 = __shfl_down(pd.y, 16, 64);
            n2 = __shfl_down(pd.z, 16, 64); n3 = __shfl_down(pd.w, 16, 64);
            px = __shfl_down(pm.x, 16, 64); py = __shfl_down(pm.y, 16, 64);
        } else {
            n0 = __shfl_up(pd.x, 16, 64); n1 = __shfl_up(pd.y, 16, 64);
            n2 = __shfl_up(pd.z, 16, 64); n3 = __shfl_up(pd.w, 16, 64);
            px = __shfl_up(pm.x, 16, 64); py = __shfl_up(pm.y, 16, 64);
        }
        __syncthreads();
        bool edge = (DIR == 0) ? ((ty & 3) == 3) : ((ty & 3) == 0);
        if (edge) {
            bool bound = (DIR == 0) ? (ty == 15) : (ty == 0);
            if (!bound) {
                int s = (DIR == 0) ? ((ty >> 2) * 16 + tx) : (((ty >> 2) - 1) * 16 + tx);
                float4 t = bd[s]; uint2 u = bm[s];
                n0 = t.x; n1 = t.y; n2 = t.z; n3 = t.w; px = u.x; py = u.y;
            } else { n0 = n1 = n2 = n3 = INFINITY; px = py = 0u; }
        }
        nb[0]=n0; nb[1]=n1; nb[2]=n2; nb[3]=n3;
        nbm[0]=(int)(short)(px & 0xffff); nbm[1]=(int)(short)(px >> 16);
        nbm[2]=(int)(short)(py & 0xffff); nbm[3]=(int)(short)(py >> 16);
    } else {
        const int c = (DIR == 2) ? 0 : 3;
        uint2 pm = packm(M[0][c], M[1][c], M[2][c], M[3][c]);
        float n0, n1, n2, n3; unsigned px, py;
        if (DIR == 2) {
            n0 = __shfl_down(D[0][c], 1, 64); n1 = __shfl_down(D[1][c], 1, 64);
            n2 = __shfl_down(D[2][c], 1, 64); n3 = __shfl_down(D[3][c], 1, 64);
            px = __shfl_down(pm.x, 1, 64); py = __shfl_down(pm.y, 1, 64);
        } else {
            n0 = __shfl_up(D[0][c], 1, 64); n1 = __shfl_up(D[1][c], 1, 64);
            n2 = __shfl_up(D[2][c], 1, 64); n3 = __shfl_up(D[3][c], 1, 64);
            px = __shfl_up(pm.x, 1, 64); py = __shfl_up(pm.y, 1, 64);
        }
        bool bound = (DIR == 2) ? (tx == 15) : (tx == 0);
        if (bound) { n0 = n1 = n2 = n3 = INFINITY; px = py = 0u; }
        nb[0]=n0; nb[1]=n1; nb[2]=n2; nb[3]=n3;
        nbm[0]=(int)(short)(px & 0xffff); nbm[1]=(int)(short)(px >> 16);
        nbm[2]=(int)(short)(py & 0xffff); nbm[3]=(int)(short)(py >> 16);
    }
    // identical arithmetic / update order to the verified kernel
    if (DIR == 0) {
        #pragma unroll
        for (int i = 0; i < 4; i++)
            #pragma unroll
            for (int j = 0; j < 4; j++) {
                float sd = (i < 3) ? D[i+1][j] : nb[j];
                int   sm = (i < 3) ? M[i+1][j] : nbm[j];
                float wd = __fadd_rn(__fadd_rn(sd, Wg[i][j]), Vv[i+1][j]);
                if (wd < D[i][j]) { D[i][j] = wd; M[i][j] = sm; }
            }
    } else if (DIR == 1) {
        #pragma unroll
        for (int i = 3; i >= 0; i--)
            #pragma unroll
            for (int j = 0; j < 4; j++) {
                float sd = (i > 0) ? D[i-1][j] : nb[j];
                int   sm = (i > 0) ? M[i-1][j] : nbm[j];
                float wd = __fadd_rn(__fadd_rn(sd, Wg[i][j]), Vv[i][j]);
                if (wd < D[i][j]) { D[i][j] = wd; M[i][j] = sm; }
            }
    } else if (DIR == 2) {
        #pragma unroll
        for (int i = 0; i < 4; i++)
            #pragma unroll
            for (int j = 0; j < 4; j++) {
                float sd = (j < 3) ? D[i][j+1] : nb[i];
                int   sm = (j < 3) ? M[i][j+1] : nbm[i];
                float wd = __fadd_rn(__fadd_rn(sd, Wg[i][j]), Hh[i][j+1]);
                if (wd < D[i][j]) { D[i][j] = wd; M[i][j] = sm; }
            }
    } else {
        #pragma unroll
        for (int i = 0; i < 4; i++)
            #pragma unroll
            for (int j = 3; j >= 0; j--) {
                float sd = (j > 0) ? D[i][j-1] : nb[i];
                int   sm = (j > 0) ? M[i][j-1] : nbm[i];
                float wd = __fadd_rn(__fadd_rn(sd, Wg[i][j]), Hh[i][j]);
                if (wd < D[i][j]) { D[i][j] = wd; M[i][j] = sm; }
            }
    }
}

// seed mode (cents != nullptr): LDS atomicMax seed tile (max-c == XLA scatter
// later-index-wins; verified). No global dist/mask read on launch 1.
__global__ __launch_bounds__(256) void prop_fused(
    const float* __restrict__ din, const short* __restrict__ min_,
    float* __restrict__ dout, short* __restrict__ mout,
    const float* __restrict__ wgm, const float* __restrict__ cwV,
    const float* __restrict__ cwH, const int* __restrict__ cents,
    int n_it, float* __restrict__ out_mask)
{
    __shared__ float4 bd0[48]; __shared__ uint2 bm0[48];
    __shared__ float4 bd1[48]; __shared__ uint2 bm1[48];
    __shared__ int seedv[64 * 64];
    int blk = blockIdx.x;
    int b = blk >> 4, tile = blk & 15;
    int ty0 = (tile >> 2) * TS, tx0 = (tile & 3) * TS;
    int tid = threadIdx.x;
    int tx = tid & 15, ty = tid >> 4;
    int gx0 = wrapc(tx0 + 4 * tx - 4);
    int cm1 = wrapc(gx0 - 1);
    int rowoff[4];
    #pragma unroll
    for (int i = 0; i < 4; i++) {
        int y = wrapc(ty0 + 4 * ty - 4 + i);
        rowoff[i] = y * W + gx0;
    }
    int rowm1 = wrapc(ty0 + 4 * ty - 5) * W + gx0;
    const float* wgmb = wgm + (size_t)b * HW;
    const float* Vb = cwV + (size_t)b * HW;
    const float* Hb = cwH + (size_t)b * HW;
    float D[4][4]; int M[4][4]; float Wg[4][4]; float Vv[5][4]; float Hh[4][5];
    {
        float4 v0 = *(const float4*)(Vb + rowm1);
        Vv[0][0] = v0.x; Vv[0][1] = v0.y; Vv[0][2] = v0.z; Vv[0][3] = v0.w;
    }
    #pragma unroll
    for (int i = 0; i < 4; i++) {
        float4 wv = *(const float4*)(wgmb + rowoff[i]);
        float4 vv = *(const float4*)(Vb + rowoff[i]);
        float4 hh = *(const float4*)(Hb + rowoff[i]);
        Wg[i][0] = wv.x; Wg[i][1] = wv.y; Wg[i][2] = wv.z; Wg[i][3] = wv.w;
        Vv[i+1][0] = vv.x; Vv[i+1][1] = vv.y; Vv[i+1][2] = vv.z; Vv[i+1][3] = vv.w;
        Hh[i][1] = hh.x; Hh[i][2] = hh.y; Hh[i][3] = hh.z; Hh[i][4] = hh.w;
        Hh[i][0] = Hb[rowoff[i] - gx0 + cm1];
    }
    if (cents) {
        for (int e = tid; e < 64 * 64; e += 256) seedv[e] = -1;
        __syncthreads();
        if (tid < C) {
            int cy = cents[(b * C + tid) * 2 + 0];
            int cx = cents[(b * C + tid) * 2 + 1];
            int ly = cy - (ty0 - 4); ly += (ly < 0) ? 224 : 0; ly -= (ly >= 224) ? 224 : 0;
            int lx = cx - (tx0 - 4); lx += (lx < 0) ? 224 : 0; lx -= (lx >= 224) ? 224 : 0;
            if (ly < 64 && lx < 64) atomicMax(&seedv[ly * 64 + lx], tid);
        }
        __syncthreads();
        #pragma unroll
        for (int i = 0; i < 4; i++)
            #pragma unroll
            for (int j = 0; j < 4; j++) {
                int s = seedv[(4 * ty + i) * 64 + 4 * tx + j];
                D[i][j] = (s >= 0) ? 0.f : INFINITY;
                M[i][j] = s;
            }
    } else {
        const float* dinb = din + (size_t)b * HW;
        const short* minb = min_ + (size_t)b * HW;
        #pragma unroll
        for (int i = 0; i < 4; i++) {
            float4 dv = *(const float4*)(dinb + rowoff[i]);
            uint2  mv = *(const uint2*)(minb + rowoff[i]);
            D[i][0] = dv.x; D[i][1] = dv.y; D[i][2] = dv.z; D[i][3] = dv.w;
            M[i][0] = (int)(short)(mv.x & 0xffff); M[i][1] = (int)(short)(mv.x >> 16);
            M[i][2] = (int)(short)(mv.y & 0xffff); M[i][3] = (int)(short)(mv.y >> 16);
        }
    }
    #pragma unroll 1
    for (int it = 0; it < n_it; ++it) {
        do_pass<0>(D, M, Wg, Vv, Hh, bd0, bm0, ty, tx);
        do_pass<1>(D, M, Wg, Vv, Hh, bd1, bm1, ty, tx);
        do_pass<2>(D, M, Wg, Vv, Hh, bd0, bm0, ty, tx);
        do_pass<3>(D, M, Wg, Vv, Hh, bd1, bm1, ty, tx);
    }
    if (ty >= 1 && ty < 15 && tx >= 1 && tx < 15) {
        if (out_mask) {
            float* omb = out_mask + (size_t)b * HW;
            #pragma unroll
            for (int i = 0; i < 4; i++)
                *(float4*)(omb + rowoff[i]) =
                    make_float4((float)M[i][0], (float)M[i][1], (float)M[i][2], (float)M[i][3]);
        } else {
            float* doutb = dout + (size_t)b * HW;
            short* moutb = mout + (size_t)b * HW;
            #pragma unroll
            for (int i = 0; i < 4; i++) {
                *(float4*)(doutb + rowoff[i]) = make_float4(D[i][0], D[i][1], D[i][2], D[i][3]);
                *(uint2*)(moutb + rowoff[i]) = packm(M[i][0], M[i][1], M[i][2], M[i][3]);
            }
        }
    }
}

extern "C" void kernel_launch(void* const* d_in, const int* in_sizes, int n_in,
                              void* d_out, int out_size, void* d_ws, size_t ws_size,
                              hipStream_t stream) {
    const float* x   = (const float*)d_in[0];
    const float* wgt = (const float*)d_in[1];
    float* out = (float*)d_out;
    float* out_grad  = out;
    float* out_cents = out + (size_t)B * HW;
    float* out_mask  = out + (size_t)B * HW + (size_t)B * C * 2;

    char* ws = (char*)d_ws;
    const size_t n = (size_t)B * HW;
    float* wgm    = (float*)ws;                ws += sizeof(float) * n;
    float* cwV    = (float*)ws;                ws += sizeof(float) * n;
    float* cwH    = (float*)ws;                ws += sizeof(float) * n;
    float* dist_a = (float*)ws;                ws += sizeof(float) * n;
    float* dist_b = (float*)ws;                ws += sizeof(float) * n;
    short* mask_a = (short*)ws;                ws += sizeof(short) * n;
    short* mask_b = (short*)ws;                ws += sizeof(short) * n;
    int*   cents_i = (int*)ws;                 ws += sizeof(int) * B * C * 2;
    // cand/cnt alias dist_b: live only between cand_kernel and resolve_kernel,
    // both of which precede the first prop write of dist_b (stream-ordered).
    int* cand = (int*)dist_b;
    int* cnt  = cand + (size_t)B * C * KCAND;

    gradcw_kernel<<<B * 196, 256, 0, stream>>>(x, wgt, wgm, out_grad, cwV, cwH);
    cand_kernel<<<(B * C) / 4, 256, 0, stream>>>(out_grad, cand, cnt);
    resolve_kernel<<<B, 256, 0, stream>>>(out_grad, cand, cnt, cents_i, out_cents);

    // 13 launches: 12x4 + 1x2 = 50 iterations. Launch 1 seeds in-kernel
    // (init/seed kernels eliminated) and writes dist_b (cand/cnt already dead).
    float* da = dist_a; float* db = dist_b;
    short* ma = mask_a; short* mb = mask_b;
    int done = 0; bool first = true;
    while (done < NUM_ITERS) {
        int n_it = (NUM_ITERS - done) < 4 ? (NUM_ITERS - done) : 4;
        bool last = (done + n_it) == NUM_ITERS;
        prop_fused<<<B * 16, 256, 0, stream>>>(da, ma, db, mb, wgm, cwV, cwH,
                                               first ? cents_i : (const int*)nullptr,
                                               n_it, last ? out_mask : (float*)nullptr);
        float* td = da; da = db; db = td;
        short* tm = ma; ma = mb; mb = tm;
        done += n_it; first = false;
    }
}

// Round 6
// 418.659 us; speedup vs baseline: 2.1560x; 1.1477x over previous
//
#include <hip/hip_runtime.h>
#include <math.h>

#define H 224
#define W 224
#define C 196
#define NB 10
#define NUM_ITERS 50
#define B 64
#define HW (H*W)
#define TS 56
#define KCAND 8
#define COLOR_WEIGHT 10.0f
#define GRAD_WEIGHT 10.0f

// ---------------- fused grad map + wgm + V/H color diffs ----------------
// XCD swizzle: dispatch index d maps to XCD d%8 (8 XCDs). Remap so image b's
// blocks land on XCD b%8 -> static fields written into the same L2 the prop
// blocks of image b will read from.
__global__ __launch_bounds__(256) void gradcw_kernel(const float* __restrict__ x,
                              const float* __restrict__ wgt,
                              float* __restrict__ wgm, float* __restrict__ out_grad,
                              float* __restrict__ cwV, float* __restrict__ cwH) {
    __shared__ float gray[10][34];   // (8+2) x (32+2) halo tile
    int blk = blockIdx.x;
    int kq = blk >> 3;
    int t = kq % 196;
    int b = (blk & 7) + 8 * (kq / 196);
    int by = (t / 7) * 8;            // 28 tile-rows
    int bx = (t - (t / 7) * 7) * 32; // 7 tile-cols
    const float* xb = x + (size_t)b * 3 * HW;
    int tid = threadIdx.x;
    for (int e = tid; e < 340; e += 256) {
        int ly = e / 34, lx = e - (e / 34) * 34;
        int gy = by - 1 + ly, gx = bx - 1 + lx;
        float g = 0.f;
        if (gy >= 0 && gy < H && gx >= 0 && gx < W) {
            int q = gy * W + gx;
            g = __fadd_rn(__fadd_rn(__fmul_rn(0.2989f, xb[q]), __fmul_rn(0.587f, xb[HW + q])),
                          __fmul_rn(0.114f, xb[2 * HW + q]));
        }
        gray[ly][lx] = g;
    }
    __syncthreads();
    int ty2 = tid >> 5, tx2 = tid & 31;
    int h = by + ty2, w = bx + tx2;
    int p = h * W + w;
    int idx = b * HW + p;
    float ax = 0.f, ay = 0.f;
    #pragma unroll
    for (int ky = 0; ky < 3; ky++) {
        #pragma unroll
        for (int kx = 0; kx < 3; kx++) {
            float g = gray[ty2 + ky][tx2 + kx];
            ax = __fadd_rn(ax, __fmul_rn(wgt[ky * 3 + kx], g));
            ay = __fadd_rn(ay, __fmul_rn(wgt[9 + ky * 3 + kx], g));
        }
    }
    float s = __fadd_rn(__fadd_rn(__fmul_rn(ax, ax), __fmul_rn(ay, ay)), 1e-8f);
    float gv = sqrtf(s);
    out_grad[idx] = gv;
    wgm[idx] = __fmul_rn(powf(gv, 4.0f), GRAD_WEIGHT);  // powf kept: bit-identical

    float r0 = xb[p];
    float g0 = xb[HW + p];
    float b0 = xb[2 * HW + p];
    int hd_ = (h + 1 >= H) ? 0 : h + 1;
    int wd_ = (w + 1 >= W) ? 0 : w + 1;
    int qd = hd_ * W + w;
    int qr = h * W + wd_;
    float dv = __fadd_rn(__fadd_rn(fabsf(__fsub_rn(r0, xb[qd])), fabsf(__fsub_rn(g0, xb[HW + qd]))),
                         fabsf(__fsub_rn(b0, xb[2 * HW + qd])));
    float dh = __fadd_rn(__fadd_rn(fabsf(__fsub_rn(r0, xb[qr])), fabsf(__fsub_rn(g0, xb[HW + qr]))),
                         fabsf(__fsub_rn(b0, xb[2 * HW + qr])));
    cwV[idx] = __fmul_rn(dv, COLOR_WEIGHT);
    cwH[idx] = __fmul_rn(dh, COLOR_WEIGHT);
}

// ---------------- parallel per-centroid window argmin (candidates) ----------------
__global__ void cand_kernel(const float* __restrict__ grad, int* __restrict__ cand,
                            int* __restrict__ cnt) {
    int gtid = blockIdx.x * blockDim.x + threadIdx.x;
    int wid = gtid >> 6;
    int lane = threadIdx.x & 63;
    if (wid >= B * C) return;
    int b = wid / C, c = wid - b * C;
    const float* gb = grad + (size_t)b * HW;
    int cy = 8 + 16 * (c / 14), cx = 8 + 16 * (c % 14);
    int ymin = max(0, cy - NB), ymax = min(H, cy + NB);
    int xmin = max(0, cx - NB), xmax = min(W, cx + NB);
    int rh = ymax - ymin, rw = xmax - xmin;
    float v[7];
    float lmin = INFINITY;
    #pragma unroll
    for (int i = 0; i < 7; i++) {
        int cell = lane + 64 * i;
        float val = INFINITY;
        if (cell < 400) {
            int r = cell / 20, cc = cell - (cell / 20) * 20;
            if (r < rh && cc < rw) val = gb[(ymin + r) * W + xmin + cc];
        }
        v[i] = val;
        lmin = fminf(lmin, val);
    }
    #pragma unroll
    for (int m = 1; m < 64; m <<= 1) lmin = fminf(lmin, __shfl_xor(lmin, m, 64));
    float mv = lmin;
    int n = 0;
    int base = wid * KCAND;
    #pragma unroll
    for (int i = 0; i < 7; i++) {
        unsigned long long msk = __ballot(v[i] == mv);
        if (lane == 0) {
            while (msk) {
                int bit = __ffsll(msk) - 1;
                msk &= msk - 1;
                int cell = bit + 64 * i;
                if (n < KCAND) {
                    int r = cell / 20, cc = cell - (cell / 20) * 20;
                    cand[base + n] = (ymin + r) * W + (xmin + cc);
                }
                n++;
            }
        }
    }
    if (lane == 0) cnt[wid] = n;
}

// ---------------- wavefront-parallel occupancy resolve ----------------
__global__ void resolve_kernel(const float* __restrict__ grad,
                               const int* __restrict__ cand, const int* __restrict__ cnt,
                               int* __restrict__ cents_i, float* __restrict__ out_cents) {
    __shared__ unsigned char occ[HW];
    __shared__ int scand[C * KCAND];
    __shared__ int scnt[C];
    int b = blockIdx.x;
    int t = threadIdx.x;
    for (int i = t; i < HW / 4; i += 256) ((int*)occ)[i] = 0;
    for (int i = t; i < C * KCAND; i += 256) scand[i] = cand[b * C * KCAND + i];
    for (int i = t; i < C; i += 256) scnt[i] = cnt[b * C + i];
    __syncthreads();
    int c = t;
    int gi = c / 14, gj = c - 14 * (c / 14);
    int myround = 2 * gi + gj;
    for (int r = 0; r < 40; r++) {
        if (c < C && myround == r) {
            int n = scnt[c];
            int ny = 0, nx = 0;
            bool found = false;
            if (n <= KCAND) {
                for (int k = 0; k < n; k++) {
                    int pos = scand[c * KCAND + k];
                    if (!occ[pos]) {
                        found = true; ny = pos / W; nx = pos - (pos / W) * W;
                        occ[pos] = 1; break;
                    }
                }
            } else {
                const float* gb = grad + (size_t)b * HW;
                int cy = 8 + 16 * gi, cx = 8 + 16 * gj;
                int ymin = max(0, cy - NB), ymax = min(H, cy + NB);
                int xmin = max(0, cx - NB), xmax = min(W, cx + NB);
                float mv = INFINITY;
                for (int rr = ymin; rr < ymax; rr++)
                    for (int cc = xmin; cc < xmax; cc++)
                        mv = fminf(mv, gb[rr * W + cc]);
                for (int rr = ymin; rr < ymax && !found; rr++)
                    for (int cc = xmin; cc < xmax && !found; cc++)
                        if (gb[rr * W + cc] == mv && !occ[rr * W + cc]) {
                            found = true; ny = rr; nx = cc; occ[rr * W + cc] = 1;
                        }
            }
            if (!found) { ny = 8 + 16 * gi; nx = 8 + 16 * gj; }
            cents_i[(b * C + c) * 2 + 0] = ny;
            cents_i[(b * C + c) * 2 + 1] = nx;
            out_cents[(b * C + c) * 2 + 0] = (float)ny;
            out_cents[(b * C + c) * 2 + 1] = (float)nx;
        }
        __syncthreads();
    }
}

// ---------------- fused propagation: shfl transport, 2 barriers/iter ----------------
// Wave layout: 256 threads, tx=tid&15, ty=tid>>4 -> one wave = 4 full thread-rows.
// Horizontal passes: pure shfl. Vertical passes: shfl + 16-thread LDS exchange.
// __launch_bounds__(256,3): cap 168 VGPR (loop-live state ~130 -> no spill
// expected), 3 blocks/CU vs 2 uncapped -> more cross-generation load/compute
// overlap. NOTE (256,4) caps at 128 and SPILLS (r4: +90MB scratch/dispatch).
__device__ __forceinline__ int wrapc(int v) {
    v += (v < 0) ? 224 : 0;
    v -= (v >= 224) ? 224 : 0;
    return v;
}
__device__ __forceinline__ uint2 packm(int a, int b_, int c_, int d_) {
    uint2 r;
    r.x = (a & 0xffff) | (b_ << 16);
    r.y = (c_ & 0xffff) | (d_ << 16);
    return r;
}

template<int DIR>
__device__ __forceinline__ void do_pass(float (&D)[4][4], int (&M)[4][4],
    const float (&Wg)[4][4], const float (&Vv)[5][4], const float (&Hh)[4][5],
    float4* __restrict__ bd, uint2* __restrict__ bm, int ty, int tx)
{
    float nb[4]; int nbm[4];
    if (DIR == 0 || DIR == 1) {
        const int r = (DIR == 0) ? 0 : 3;
        float4 pd = make_float4(D[r][0], D[r][1], D[r][2], D[r][3]);
        uint2 pm = packm(M[r][0], M[r][1], M[r][2], M[r][3]);
        bool pub = (DIR == 0) ? (((ty & 3) == 0) && ty > 0)
                              : (((ty & 3) == 3) && ty < 15);
        if (pub) {
            int ps = (DIR == 0) ? (((ty >> 2) - 1) * 16 + tx) : ((ty >> 2) * 16 + tx);
            bd[ps] = pd; bm[ps] = pm;
        }
        float n0, n1, n2, n3; unsigned px, py;
        if (DIR == 0) {
            n0 = __shfl_down(pd.x, 16, 64); n1 = __shfl_down(pd.y, 16, 64);
            n2 = __shfl_down(pd.z, 16, 64); n3 = __shfl_down(pd.w, 16, 64);
            px = __shfl_down(pm.x, 16, 64); py = __shfl_down(pm.y, 16, 64);
        } else {
            n0 = __shfl_up(pd.x, 16, 64); n1 = __shfl_up(pd.y, 16, 64);
            n2 = __shfl_up(pd.z, 16, 64); n3 = __shfl_up(pd.w, 16, 64);
            px = __shfl_up(pm.x, 16, 64); py = __shfl_up(pm.y, 16, 64);
        }
        __syncthreads();
        bool edge = (DIR == 0) ? ((ty & 3) == 3) : ((ty & 3) == 0);
        if (edge) {
            bool bound = (DIR == 0) ? (ty == 15) : (ty == 0);
            if (!bound) {
                int s = (DIR == 0) ? ((ty >> 2) * 16 + tx) : (((ty >> 2) - 1) * 16 + tx);
                float4 t = bd[s]; uint2 u = bm[s];
                n0 = t.x; n1 = t.y; n2 = t.z; n3 = t.w; px = u.x; py = u.y;
            } else { n0 = n1 = n2 = n3 = INFINITY; px = py = 0u; }
        }
        nb[0]=n0; nb[1]=n1; nb[2]=n2; nb[3]=n3;
        nbm[0]=(int)(short)(px & 0xffff); nbm[1]=(int)(short)(px >> 16);
        nbm[2]=(int)(short)(py & 0xffff); nbm[3]=(int)(short)(py >> 16);
    } else {
        const int c = (DIR == 2) ? 0 : 3;
        uint2 pm = packm(M[0][c], M[1][c], M[2][c], M[3][c]);
        float n0, n1, n2, n3; unsigned px, py;
        if (DIR == 2) {
            n0 = __shfl_down(D[0][c], 1, 64); n1 = __shfl_down(D[1][c], 1, 64);
            n2 = __shfl_down(D[2][c], 1, 64); n3 = __shfl_down(D[3][c], 1, 64);
            px = __shfl_down(pm.x, 1, 64); py = __shfl_down(pm.y, 1, 64);
        } else {
            n0 = __shfl_up(D[0][c], 1, 64); n1 = __shfl_up(D[1][c], 1, 64);
            n2 = __shfl_up(D[2][c], 1, 64); n3 = __shfl_up(D[3][c], 1, 64);
            px = __shfl_up(pm.x, 1, 64); py = __shfl_up(pm.y, 1, 64);
        }
        bool bound = (DIR == 2) ? (tx == 15) : (tx == 0);
        if (bound) { n0 = n1 = n2 = n3 = INFINITY; px = py = 0u; }
        nb[0]=n0; nb[1]=n1; nb[2]=n2; nb[3]=n3;
        nbm[0]=(int)(short)(px & 0xffff); nbm[1]=(int)(short)(px >> 16);
        nbm[2]=(int)(short)(py & 0xffff); nbm[3]=(int)(short)(py >> 16);
    }
    // identical arithmetic / update order to the verified kernel
    if (DIR == 0) {
        #pragma unroll
        for (int i = 0; i < 4; i++)
            #pragma unroll
            for (int j = 0; j < 4; j++) {
                float sd = (i < 3) ? D[i+1][j] : nb[j];
                int   sm = (i < 3) ? M[i+1][j] : nbm[j];
                float wd = __fadd_rn(__fadd_rn(sd, Wg[i][j]), Vv[i+1][j]);
                if (wd < D[i][j]) { D[i][j] = wd; M[i][j] = sm; }
            }
    } else if (DIR == 1) {
        #pragma unroll
        for (int i = 3; i >= 0; i--)
            #pragma unroll
            for (int j = 0; j < 4; j++) {
                float sd = (i > 0) ? D[i-1][j] : nb[j];
                int   sm = (i > 0) ? M[i-1][j] : nbm[j];
                float wd = __fadd_rn(__fadd_rn(sd, Wg[i][j]), Vv[i][j]);
                if (wd < D[i][j]) { D[i][j] = wd; M[i][j] = sm; }
            }
    } else if (DIR == 2) {
        #pragma unroll
        for (int i = 0; i < 4; i++)
            #pragma unroll
            for (int j = 0; j < 4; j++) {
                float sd = (j < 3) ? D[i][j+1] : nb[i];
                int   sm = (j < 3) ? M[i][j+1] : nbm[i];
                float wd = __fadd_rn(__fadd_rn(sd, Wg[i][j]), Hh[i][j+1]);
                if (wd < D[i][j]) { D[i][j] = wd; M[i][j] = sm; }
            }
    } else {
        #pragma unroll
        for (int i = 0; i < 4; i++)
            #pragma unroll
            for (int j = 3; j >= 0; j--) {
                float sd = (j > 0) ? D[i][j-1] : nb[i];
                int   sm = (j > 0) ? M[i][j-1] : nbm[i];
                float wd = __fadd_rn(__fadd_rn(sd, Wg[i][j]), Hh[i][j]);
                if (wd < D[i][j]) { D[i][j] = wd; M[i][j] = sm; }
            }
    }
}

// seed mode (cents != nullptr): LDS atomicMax seed tile (max-c == XLA scatter
// later-index-wins; verified). XCD swizzle pins all 16 tiles of image b to
// XCD b%8 across all 13 launches -> halo strips written by neighbor tiles in
// launch k are L2-resident for launch k+1.
__global__ __launch_bounds__(256, 3) void prop_fused(
    const float* __restrict__ din, const short* __restrict__ min_,
    float* __restrict__ dout, short* __restrict__ mout,
    const float* __restrict__ wgm, const float* __restrict__ cwV,
    const float* __restrict__ cwH, const int* __restrict__ cents,
    int n_it, float* __restrict__ out_mask)
{
    __shared__ float4 bd0[48]; __shared__ uint2 bm0[48];
    __shared__ float4 bd1[48]; __shared__ uint2 bm1[48];
    __shared__ int seedv[64 * 64];
    int blk = blockIdx.x;
    int q = blk >> 3;
    int tile = q & 15;
    int b = (blk & 7) + 8 * (q >> 4);
    int ty0 = (tile >> 2) * TS, tx0 = (tile & 3) * TS;
    int tid = threadIdx.x;
    int tx = tid & 15, ty = tid >> 4;
    int gx0 = wrapc(tx0 + 4 * tx - 4);
    int cm1 = wrapc(gx0 - 1);
    int rowoff[4];
    #pragma unroll
    for (int i = 0; i < 4; i++) {
        int y = wrapc(ty0 + 4 * ty - 4 + i);
        rowoff[i] = y * W + gx0;
    }
    int rowm1 = wrapc(ty0 + 4 * ty - 5) * W + gx0;
    const float* wgmb = wgm + (size_t)b * HW;
    const float* Vb = cwV + (size_t)b * HW;
    const float* Hb = cwH + (size_t)b * HW;
    float D[4][4]; int M[4][4]; float Wg[4][4]; float Vv[5][4]; float Hh[4][5];
    {
        float4 v0 = *(const float4*)(Vb + rowm1);
        Vv[0][0] = v0.x; Vv[0][1] = v0.y; Vv[0][2] = v0.z; Vv[0][3] = v0.w;
    }
    #pragma unroll
    for (int i = 0; i < 4; i++) {
        float4 wv = *(const float4*)(wgmb + rowoff[i]);
        float4 vv = *(const float4*)(Vb + rowoff[i]);
        float4 hh = *(const float4*)(Hb + rowoff[i]);
        Wg[i][0] = wv.x; Wg[i][1] = wv.y; Wg[i][2] = wv.z; Wg[i][3] = wv.w;
        Vv[i+1][0] = vv.x; Vv[i+1][1] = vv.y; Vv[i+1][2] = vv.z; Vv[i+1][3] = vv.w;
        Hh[i][1] = hh.x; Hh[i][2] = hh.y; Hh[i][3] = hh.z; Hh[i][4] = hh.w;
        Hh[i][0] = Hb[rowoff[i] - gx0 + cm1];
    }
    if (cents) {
        for (int e = tid; e < 64 * 64; e += 256) seedv[e] = -1;
        __syncthreads();
        if (tid < C) {
            int cy = cents[(b * C + tid) * 2 + 0];
            int cx = cents[(b * C + tid) * 2 + 1];
            int ly = cy - (ty0 - 4); ly += (ly < 0) ? 224 : 0; ly -= (ly >= 224) ? 224 : 0;
            int lx = cx - (tx0 - 4); lx += (lx < 0) ? 224 : 0; lx -= (lx >= 224) ? 224 : 0;
            if (ly < 64 && lx < 64) atomicMax(&seedv[ly * 64 + lx], tid);
        }
        __syncthreads();
        #pragma unroll
        for (int i = 0; i < 4; i++)
            #pragma unroll
            for (int j = 0; j < 4; j++) {
                int s = seedv[(4 * ty + i) * 64 + 4 * tx + j];
                D[i][j] = (s >= 0) ? 0.f : INFINITY;
                M[i][j] = s;
            }
    } else {
        const float* dinb = din + (size_t)b * HW;
        const short* minb = min_ + (size_t)b * HW;
        #pragma unroll
        for (int i = 0; i < 4; i++) {
            float4 dv = *(const float4*)(dinb + rowoff[i]);
            uint2  mv = *(const uint2*)(minb + rowoff[i]);
            D[i][0] = dv.x; D[i][1] = dv.y; D[i][2] = dv.z; D[i][3] = dv.w;
            M[i][0] = (int)(short)(mv.x & 0xffff); M[i][1] = (int)(short)(mv.x >> 16);
            M[i][2] = (int)(short)(mv.y & 0xffff); M[i][3] = (int)(short)(mv.y >> 16);
        }
    }
    #pragma unroll 1
    for (int it = 0; it < n_it; ++it) {
        do_pass<0>(D, M, Wg, Vv, Hh, bd0, bm0, ty, tx);
        do_pass<1>(D, M, Wg, Vv, Hh, bd1, bm1, ty, tx);
        do_pass<2>(D, M, Wg, Vv, Hh, bd0, bm0, ty, tx);
        do_pass<3>(D, M, Wg, Vv, Hh, bd1, bm1, ty, tx);
    }
    if (ty >= 1 && ty < 15 && tx >= 1 && tx < 15) {
        if (out_mask) {
            float* omb = out_mask + (size_t)b * HW;
            #pragma unroll
            for (int i = 0; i < 4; i++)
                *(float4*)(omb + rowoff[i]) =
                    make_float4((float)M[i][0], (float)M[i][1], (float)M[i][2], (float)M[i][3]);
        } else {
            float* doutb = dout + (size_t)b * HW;
            short* moutb = mout + (size_t)b * HW;
            #pragma unroll
            for (int i = 0; i < 4; i++) {
                *(float4*)(doutb + rowoff[i]) = make_float4(D[i][0], D[i][1], D[i][2], D[i][3]);
                *(uint2*)(moutb + rowoff[i]) = packm(M[i][0], M[i][1], M[i][2], M[i][3]);
            }
        }
    }
}

extern "C" void kernel_launch(void* const* d_in, const int* in_sizes, int n_in,
                              void* d_out, int out_size, void* d_ws, size_t ws_size,
                              hipStream_t stream) {
    const float* x   = (const float*)d_in[0];
    const float* wgt = (const float*)d_in[1];
    float* out = (float*)d_out;
    float* out_grad  = out;
    float* out_cents = out + (size_t)B * HW;
    float* out_mask  = out + (size_t)B * HW + (size_t)B * C * 2;

    char* ws = (char*)d_ws;
    const size_t n = (size_t)B * HW;
    float* wgm    = (float*)ws;                ws += sizeof(float) * n;
    float* cwV    = (float*)ws;                ws += sizeof(float) * n;
    float* cwH    = (float*)ws;                ws += sizeof(float) * n;
    float* dist_a = (float*)ws;                ws += sizeof(float) * n;
    float* dist_b = (float*)ws;                ws += sizeof(float) * n;
    short* mask_a = (short*)ws;                ws += sizeof(short) * n;
    short* mask_b = (short*)ws;                ws += sizeof(short) * n;
    int*   cents_i = (int*)ws;                 ws += sizeof(int) * B * C * 2;
    // cand/cnt alias dist_b: live only between cand_kernel and resolve_kernel,
    // both of which precede the first prop write of dist_b (stream-ordered).
    int* cand = (int*)dist_b;
    int* cnt  = cand + (size_t)B * C * KCAND;

    gradcw_kernel<<<B * 196, 256, 0, stream>>>(x, wgt, wgm, out_grad, cwV, cwH);
    cand_kernel<<<(B * C) / 4, 256, 0, stream>>>(out_grad, cand, cnt);
    resolve_kernel<<<B, 256, 0, stream>>>(out_grad, cand, cnt, cents_i, out_cents);

    // 13 launches: 12x4 + 1x2 = 50 iterations. Launch 1 seeds in-kernel
    // (init/seed kernels eliminated) and writes dist_b (cand/cnt already dead).
    float* da = dist_a; float* db = dist_b;
    short* ma = mask_a; short* mb = mask_b;
    int done = 0; bool first = true;
    while (done < NUM_ITERS) {
        int n_it = (NUM_ITERS - done) < 4 ? (NUM_ITERS - done) : 4;
        bool last = (done + n_it) == NUM_ITERS;
        prop_fused<<<B * 16, 256, 0, stream>>>(da, ma, db, mb, wgm, cwV, cwH,
                                               first ? cents_i : (const int*)nullptr,
                                               n_it, last ? out_mask : (float*)nullptr);
        float* td = da; da = db; db = td;
        short* tm = ma; ma = mb; mb = tm;
        done += n_it; first = false;
    }
}